// Round 2
// baseline (2635.609 us; speedup 1.0000x reference)
//
#include <hip/hip_runtime.h>

#define NS 131072
#define KC 2048
#define DD 256

#define BM 64
#define BN 64
#define BK 32

// ---------------- init: zero accumulators ----------------
__global__ void k_init(float* __restrict__ segc, int* __restrict__ cnt,
                       double* __restrict__ loss) {
  int i = blockIdx.x * 256 + threadIdx.x;
  if (i < KC * DD) segc[i] = 0.0f;
  if (i < KC) cnt[i] = 0;
  if (i == 0) *loss = 0.0;
}

// ---------------- row norms, numpy-pairwise-exact fp32 ----------------
// Replicates np.sum(a*a, axis=1) for row length 256:
// pairwise_sum splits 256 -> 128+128; each 128 uses 8 accumulator chains
// r[j] += sq[8i+j], combined ((r0+r1)+(r2+r3))+((r4+r5)+(r6+r7)); then
// half0+half1. 8 lanes cooperate per row; lane j owns chain j.
__global__ __launch_bounds__(256) void k_rownorm(const float* __restrict__ A,
                                                 float* __restrict__ out,
                                                 int nrows) {
  int g = blockIdx.x * 256 + threadIdx.x;
  int row = g >> 3;
  int l = g & 7;
  if (row >= nrows) return;
  const float* p = A + (size_t)row * DD;
  float halfs[2];
  #pragma unroll
  for (int h = 0; h < 2; ++h) {
    const float* q = p + h * 128;
    float x = q[l];
    float r = __fmul_rn(x, x);
    #pragma unroll
    for (int i = 8; i < 128; i += 8) {
      float y = q[i + l];
      r = __fadd_rn(r, __fmul_rn(y, y));
    }
    // exact numpy combine tree at lane 0 of each 8-lane group
    float t = __fadd_rn(r, __shfl_xor(r, 1));
    t = __fadd_rn(t, __shfl_xor(t, 2));
    t = __fadd_rn(t, __shfl_xor(t, 4));
    halfs[h] = t;
  }
  if (l == 0) out[row] = __fadd_rn(halfs[0], halfs[1]);
}

// ---------------- fused GEMM + argmin, fp32-faithful ----------------
// dot accumulated as a strictly sequential fmaf chain over k ascending
// (matches BLAS sgemm microkernel accumulation). dist evaluated exactly as
// numpy: (x2 - 2*dot) + c2, left to right, no contraction.
__global__ __launch_bounds__(256) void k_argmin(
    const float* __restrict__ E, const float* __restrict__ C,
    const float* __restrict__ x2, const float* __restrict__ c2,
    int* __restrict__ labels) {
  __shared__ float As[BK][BM];
  __shared__ float Bs[BK][BN];
  __shared__ float rm1[BM][17];
  __shared__ int   rl1[BM][17];

  const int tid = threadIdx.x;
  const int tx = tid & 15, ty = tid >> 4;
  const int rowBase = blockIdx.x * BM;

  float xr[4];
  #pragma unroll
  for (int i = 0; i < 4; ++i) xr[i] = x2[rowBase + ty * 4 + i];

  float m1[4]; int l1[4];
  #pragma unroll
  for (int i = 0; i < 4; ++i) { m1[i] = 3.4e38f; l1[i] = 0; }

  for (int jc = 0; jc < KC; jc += BN) {
    float acc[4][4];
    #pragma unroll
    for (int i = 0; i < 4; ++i)
      #pragma unroll
      for (int j = 0; j < 4; ++j) acc[i][j] = 0.0f;

    for (int kk = 0; kk < DD; kk += BK) {
      #pragma unroll
      for (int s = 0; s < 2; ++s) {
        int idx = tid + s * 256;
        int r = idx >> 3, k4 = idx & 7;
        float4 v = *reinterpret_cast<const float4*>(
            E + (size_t)(rowBase + r) * DD + kk + k4 * 4);
        As[k4 * 4 + 0][r] = v.x; As[k4 * 4 + 1][r] = v.y;
        As[k4 * 4 + 2][r] = v.z; As[k4 * 4 + 3][r] = v.w;
      }
      #pragma unroll
      for (int s = 0; s < 2; ++s) {
        int idx = tid + s * 256;
        int r = idx >> 3, k4 = idx & 7;
        float4 v = *reinterpret_cast<const float4*>(
            C + (size_t)(jc + r) * DD + kk + k4 * 4);
        Bs[k4 * 4 + 0][r] = v.x; Bs[k4 * 4 + 1][r] = v.y;
        Bs[k4 * 4 + 2][r] = v.z; Bs[k4 * 4 + 3][r] = v.w;
      }
      __syncthreads();
      #pragma unroll
      for (int k = 0; k < BK; ++k) {
        float4 a = *reinterpret_cast<const float4*>(&As[k][ty * 4]);
        float4 b = *reinterpret_cast<const float4*>(&Bs[k][tx * 4]);
        float av[4] = {a.x, a.y, a.z, a.w};
        float bv[4] = {b.x, b.y, b.z, b.w};
        #pragma unroll
        for (int i = 0; i < 4; ++i)
          #pragma unroll
          for (int j = 0; j < 4; ++j)
            acc[i][j] = fmaf(av[i], bv[j], acc[i][j]);
      }
      __syncthreads();
    }
    // epilogue: numpy-exact dist + first-min argmin
    #pragma unroll
    for (int j = 0; j < 4; ++j) {
      int lab = jc + tx * 4 + j;
      float cc = c2[lab];
      #pragma unroll
      for (int i = 0; i < 4; ++i) {
        float d = __fadd_rn(__fsub_rn(xr[i], __fmul_rn(2.0f, acc[i][j])), cc);
        if (d < m1[i]) { m1[i] = d; l1[i] = lab; }
      }
    }
  }
  // cross-thread (tx) reduce per row; ties -> lowest index (numpy argmin)
  #pragma unroll
  for (int i = 0; i < 4; ++i) {
    int r = ty * 4 + i;
    rm1[r][tx] = m1[i]; rl1[r][tx] = l1[i];
  }
  __syncthreads();
  if (tid < BM) {
    float bm1 = 3.4e38f; int bl = 0;
    for (int t = 0; t < 16; ++t) {
      float v1 = rm1[tid][t]; int vl = rl1[tid][t];
      if (v1 < bm1 || (v1 == bm1 && vl < bl)) { bm1 = v1; bl = vl; }
    }
    labels[rowBase + tid] = bl;
  }
}

// ---------------- accumulate seg sums, counts, loss; emit float labels ----
__global__ __launch_bounds__(256) void k_accum(
    const float* __restrict__ E, const float* __restrict__ C,
    const int* __restrict__ labels, float* __restrict__ seg,
    int* __restrict__ cnt, double* __restrict__ loss,
    float* __restrict__ out_labels) {
  int d = threadIdx.x;  // 256 threads = 256 dims
  double lpd = 0.0;
  for (int row = blockIdx.x; row < NS; row += gridDim.x) {
    int lab = labels[row];
    float x = E[(size_t)row * DD + d];
    float c = C[(size_t)lab * DD + d];
    unsafeAtomicAdd(&seg[(size_t)lab * DD + d], x);
    float diff = x - c;
    lpd += (double)diff * (double)diff;
    if (d == 0) {
      atomicAdd(&cnt[lab], 1);
      out_labels[row] = (float)lab;
    }
  }
  #pragma unroll
  for (int o = 32; o >= 1; o >>= 1) lpd += __shfl_down(lpd, o);
  __shared__ double wsum[4];
  int lane = threadIdx.x & 63, wave = threadIdx.x >> 6;
  if (lane == 0) wsum[wave] = lpd;
  __syncthreads();
  if (threadIdx.x == 0) {
    double t = wsum[0] + wsum[1] + wsum[2] + wsum[3];
    unsafeAtomicAdd(loss, t);
  }
}

// ---------------- finalize centers, counts, loss ----------------
__global__ void k_final(const float* __restrict__ C, const int* __restrict__ counts0,
                        const int* __restrict__ cnt, float* __restrict__ out_centers,
                        float* __restrict__ out_counts, float* __restrict__ out_loss,
                        const double* __restrict__ loss) {
  int i = blockIdx.x * 256 + threadIdx.x;
  if (i < KC * DD) {
    int k = i >> 8;
    float c0 = (float)counts0[k];
    float nc = (float)(counts0[k] + cnt[k]);
    out_centers[i] = (c0 * C[i] + out_centers[i]) / nc;
  }
  if (i < KC) out_counts[i] = (float)(counts0[i] + cnt[i]);
  if (i == 0) out_loss[0] = (float)(loss[0] / (double)NS);
}

extern "C" void kernel_launch(void* const* d_in, const int* in_sizes, int n_in,
                              void* d_out, int out_size, void* d_ws, size_t ws_size,
                              hipStream_t stream) {
  const float* E = (const float*)d_in[0];
  const float* C = (const float*)d_in[1];
  const int* counts0 = (const int*)d_in[2];

  float* out = (float*)d_out;
  float* out_labels  = out;                       // [NS]
  float* out_loss    = out + NS;                  // [1]
  float* out_centers = out + NS + 1;              // [KC*DD] (doubles as seg acc)
  float* out_counts  = out + NS + 1 + KC * DD;    // [KC]

  char* ws = (char*)d_ws;
  double* loss_acc = (double*)ws;                              // 8B (+8 pad)
  int* labels      = (int*)(ws + 16);                          // NS ints
  float* x2        = (float*)(ws + 16 + 4 * (size_t)NS);       // NS floats
  float* c2        = (float*)(ws + 16 + 8 * (size_t)NS);       // KC floats
  int* cnt         = (int*)(ws + 16 + 8 * (size_t)NS + 4 * KC);// KC ints

  hipLaunchKernelGGL(k_init, dim3((KC * DD + 255) / 256), dim3(256), 0, stream,
                     out_centers, cnt, loss_acc);
  hipLaunchKernelGGL(k_rownorm, dim3(NS * 8 / 256), dim3(256), 0, stream,
                     E, x2, NS);
  hipLaunchKernelGGL(k_rownorm, dim3(KC * 8 / 256), dim3(256), 0, stream,
                     C, c2, KC);
  hipLaunchKernelGGL(k_argmin, dim3(NS / BM), dim3(256), 0, stream,
                     E, C, x2, c2, labels);
  hipLaunchKernelGGL(k_accum, dim3(1024), dim3(256), 0, stream,
                     E, C, labels, out_centers, cnt, loss_acc, out_labels);
  hipLaunchKernelGGL(k_final, dim3((KC * DD + 255) / 256), dim3(256), 0, stream,
                     C, counts0, cnt, out_centers, out_counts, out_loss, loss_acc);
}

// Round 3
// 2058.106 us; speedup vs baseline: 1.2806x; 1.2806x over previous
//
#include <hip/hip_runtime.h>

typedef float f32x2 __attribute__((ext_vector_type(2)));

#define NS 131072
#define KC 2048
#define DD 256

#define BM 128
#define BN 128
#define BK 32

// ---------------- init: zero accumulators, set argmin keys to +inf --------
__global__ void k_init(float* __restrict__ segc, int* __restrict__ cnt,
                       double* __restrict__ loss,
                       unsigned long long* __restrict__ keys) {
  int i = blockIdx.x * 256 + threadIdx.x;
  if (i < KC * DD) segc[i] = 0.0f;
  if (i < KC) cnt[i] = 0;
  if (i < NS) keys[i] = ~0ull;
  if (i == 0) *loss = 0.0;
}

// ---------------- row norms, numpy-pairwise-exact fp32 ----------------
__global__ __launch_bounds__(256) void k_rownorm(const float* __restrict__ A,
                                                 float* __restrict__ out,
                                                 int nrows) {
  int g = blockIdx.x * 256 + threadIdx.x;
  int row = g >> 3;
  int l = g & 7;
  if (row >= nrows) return;
  const float* p = A + (size_t)row * DD;
  float halfs[2];
  #pragma unroll
  for (int h = 0; h < 2; ++h) {
    const float* q = p + h * 128;
    float x = q[l];
    float r = __fmul_rn(x, x);
    #pragma unroll
    for (int i = 8; i < 128; i += 8) {
      float y = q[i + l];
      r = __fadd_rn(r, __fmul_rn(y, y));
    }
    float t = __fadd_rn(r, __shfl_xor(r, 1));
    t = __fadd_rn(t, __shfl_xor(t, 2));
    t = __fadd_rn(t, __shfl_xor(t, 4));
    halfs[h] = t;
  }
  if (l == 0) out[row] = __fadd_rn(halfs[0], halfs[1]);
}

// ---------------- fused GEMM + argmin, fp32-faithful, 128x128 tile --------
__global__ __launch_bounds__(256) void k_argmin(
    const float* __restrict__ E, const float* __restrict__ C,
    const float* __restrict__ x2, const float* __restrict__ c2,
    unsigned long long* __restrict__ keys) {
  __shared__ float smem[2 * BK * BM];     // As[32][128] | Bs[32][128] = 32 KB
  float* As = smem;
  float* Bs = smem + BK * BM;

  const int tid = threadIdx.x;
  const int tx = tid & 15, ty = tid >> 4;       // compute mapping
  const int rg = tid >> 3, kg = tid & 7;        // staging mapping
  const int rowBase = blockIdx.x * BM;
  const int colBase = blockIdx.y * BN;

  float xr[8];
  #pragma unroll
  for (int i = 0; i < 4; ++i) {
    xr[i]     = x2[rowBase + ty * 4 + i];
    xr[4 + i] = x2[rowBase + 64 + ty * 4 + i];
  }

  f32x2 acc[8][4];
  #pragma unroll
  for (int i = 0; i < 8; ++i)
    #pragma unroll
    for (int jp = 0; jp < 4; ++jp) acc[i][jp] = (f32x2){0.0f, 0.0f};

  // prefetch registers (4 rows x one k-quad each, for A and B)
  float4 va[4], vb[4];
  #pragma unroll
  for (int i = 0; i < 4; ++i) {
    va[i] = *reinterpret_cast<const float4*>(
        E + (size_t)(rowBase + rg * 4 + i) * DD + kg * 4);
    vb[i] = *reinterpret_cast<const float4*>(
        C + (size_t)(colBase + rg * 4 + i) * DD + kg * 4);
  }

  for (int kk = 0; kk < DD; kk += BK) {
    __syncthreads();  // previous FMA reads done before overwrite
    // register 4x4 transpose -> b128 LDS writes (k-major layout)
    #pragma unroll
    for (int c = 0; c < 4; ++c) {
      float4 wa, wb;
      wa.x = ((const float*)&va[0])[c]; wa.y = ((const float*)&va[1])[c];
      wa.z = ((const float*)&va[2])[c]; wa.w = ((const float*)&va[3])[c];
      wb.x = ((const float*)&vb[0])[c]; wb.y = ((const float*)&vb[1])[c];
      wb.z = ((const float*)&vb[2])[c]; wb.w = ((const float*)&vb[3])[c];
      *reinterpret_cast<float4*>(As + (kg * 4 + c) * BM + rg * 4) = wa;
      *reinterpret_cast<float4*>(Bs + (kg * 4 + c) * BN + rg * 4) = wb;
    }
    __syncthreads();
    // prefetch next k-slab while FMAs run
    if (kk + BK < DD) {
      #pragma unroll
      for (int i = 0; i < 4; ++i) {
        va[i] = *reinterpret_cast<const float4*>(
            E + (size_t)(rowBase + rg * 4 + i) * DD + kk + BK + kg * 4);
        vb[i] = *reinterpret_cast<const float4*>(
            C + (size_t)(colBase + rg * 4 + i) * DD + kk + BK + kg * 4);
      }
    }
    #pragma unroll 4
    for (int k = 0; k < BK; ++k) {
      float4 alo = *reinterpret_cast<const float4*>(As + k * BM + ty * 4);
      float4 ahi = *reinterpret_cast<const float4*>(As + k * BM + 64 + ty * 4);
      float4 blo = *reinterpret_cast<const float4*>(Bs + k * BN + tx * 4);
      float4 bhi = *reinterpret_cast<const float4*>(Bs + k * BN + 64 + tx * 4);
      f32x2 b2[4];
      b2[0] = (f32x2){blo.x, blo.y}; b2[1] = (f32x2){blo.z, blo.w};
      b2[2] = (f32x2){bhi.x, bhi.y}; b2[3] = (f32x2){bhi.z, bhi.w};
      float av[8] = {alo.x, alo.y, alo.z, alo.w, ahi.x, ahi.y, ahi.z, ahi.w};
      #pragma unroll
      for (int i = 0; i < 8; ++i) {
        f32x2 a2 = (f32x2){av[i], av[i]};
        #pragma unroll
        for (int jp = 0; jp < 4; ++jp)
#if __has_builtin(__builtin_elementwise_fma)
          acc[i][jp] = __builtin_elementwise_fma(a2, b2[jp], acc[i][jp]);
#else
          { acc[i][jp][0] = fmaf(a2[0], b2[jp][0], acc[i][jp][0]);
            acc[i][jp][1] = fmaf(a2[1], b2[jp][1], acc[i][jp][1]); }
#endif
      }
    }
  }

  // epilogue: numpy-exact dist, thread-local argmin over 8 centers/row
  float c2v[8];
  #pragma unroll
  for (int j = 0; j < 4; ++j) {
    c2v[j]     = c2[colBase + tx * 4 + j];
    c2v[4 + j] = c2[colBase + 64 + tx * 4 + j];
  }
  float m[8]; int l[8];
  #pragma unroll
  for (int i = 0; i < 8; ++i) { m[i] = 3.4e38f; l[i] = 0; }
  #pragma unroll
  for (int i = 0; i < 8; ++i) {
    #pragma unroll
    for (int g = 0; g < 2; ++g) {
      #pragma unroll
      for (int jj = 0; jj < 4; ++jj) {   // ascending center order
        int jp = g * 2 + (jj >> 1);
        float dot = acc[i][jp][jj & 1];
        float d = __fadd_rn(__fsub_rn(xr[i], __fmul_rn(2.0f, dot)), c2v[g * 4 + jj]);
        int lab = colBase + g * 64 + tx * 4 + jj;
        if (d < m[i]) { m[i] = d; l[i] = lab; }
      }
    }
  }

  // cross-thread reduce per row (alias smem), then global atomicMin key
  __syncthreads();
  float* rm = smem;                       // [128][17]
  int*   rl = (int*)(smem + BM * 17);     // [128][17]
  #pragma unroll
  for (int i = 0; i < 8; ++i) {
    int r = (i < 4) ? (ty * 4 + i) : (64 + ty * 4 + i - 4);
    rm[r * 17 + tx] = m[i];
    rl[r * 17 + tx] = l[i];
  }
  __syncthreads();
  if (tid < BM) {
    float bm = 3.4e38f; int bl = 0x7fffffff;
    for (int t = 0; t < 16; ++t) {
      float v = rm[tid * 17 + t]; int vl = rl[tid * 17 + t];
      if (v < bm || (v == bm && vl < bl)) { bm = v; bl = vl; }
    }
    unsigned u = __float_as_uint(bm);
    unsigned s = (u & 0x80000000u) ? ~u : (u | 0x80000000u);
    unsigned long long key = ((unsigned long long)s << 32) | (unsigned)bl;
    atomicMin(&keys[rowBase + tid], key);
  }
}

// ---------------- accumulate seg sums, counts, loss; emit float labels ----
__global__ __launch_bounds__(256) void k_accum(
    const float* __restrict__ E, const float* __restrict__ C,
    const unsigned long long* __restrict__ keys, float* __restrict__ seg,
    int* __restrict__ cnt, double* __restrict__ loss,
    float* __restrict__ out_labels) {
  int d = threadIdx.x;
  double lpd = 0.0;
  for (int row = blockIdx.x; row < NS; row += gridDim.x) {
    int lab = (int)(keys[row] & 0xffffffffull);
    float x = E[(size_t)row * DD + d];
    float c = C[(size_t)lab * DD + d];
    unsafeAtomicAdd(&seg[(size_t)lab * DD + d], x);
    float diff = x - c;
    lpd += (double)diff * (double)diff;
    if (d == 0) {
      atomicAdd(&cnt[lab], 1);
      out_labels[row] = (float)lab;
    }
  }
  #pragma unroll
  for (int o = 32; o >= 1; o >>= 1) lpd += __shfl_down(lpd, o);
  __shared__ double wsum[4];
  int lane = threadIdx.x & 63, wave = threadIdx.x >> 6;
  if (lane == 0) wsum[wave] = lpd;
  __syncthreads();
  if (threadIdx.x == 0) {
    double t = wsum[0] + wsum[1] + wsum[2] + wsum[3];
    unsafeAtomicAdd(loss, t);
  }
}

// ---------------- finalize centers, counts, loss ----------------
__global__ void k_final(const float* __restrict__ C, const int* __restrict__ counts0,
                        const int* __restrict__ cnt, float* __restrict__ out_centers,
                        float* __restrict__ out_counts, float* __restrict__ out_loss,
                        const double* __restrict__ loss) {
  int i = blockIdx.x * 256 + threadIdx.x;
  if (i < KC * DD) {
    int k = i >> 8;
    float c0 = (float)counts0[k];
    float nc = (float)(counts0[k] + cnt[k]);
    out_centers[i] = (c0 * C[i] + out_centers[i]) / nc;
  }
  if (i < KC) out_counts[i] = (float)(counts0[i] + cnt[i]);
  if (i == 0) out_loss[0] = (float)(loss[0] / (double)NS);
}

extern "C" void kernel_launch(void* const* d_in, const int* in_sizes, int n_in,
                              void* d_out, int out_size, void* d_ws, size_t ws_size,
                              hipStream_t stream) {
  const float* E = (const float*)d_in[0];
  const float* C = (const float*)d_in[1];
  const int* counts0 = (const int*)d_in[2];

  float* out = (float*)d_out;
  float* out_labels  = out;                       // [NS]
  float* out_loss    = out + NS;                  // [1]
  float* out_centers = out + NS + 1;              // [KC*DD] (doubles as seg acc)
  float* out_counts  = out + NS + 1 + KC * DD;    // [KC]

  char* ws = (char*)d_ws;
  double* loss_acc = (double*)ws;                                  // 16B slot
  unsigned long long* keys = (unsigned long long*)(ws + 16);       // NS u64
  float* x2 = (float*)(ws + 16 + 8 * (size_t)NS);                  // NS floats
  float* c2 = (float*)(ws + 16 + 12 * (size_t)NS);                 // KC floats
  int* cnt  = (int*)(ws + 16 + 12 * (size_t)NS + 4 * KC);          // KC ints

  hipLaunchKernelGGL(k_init, dim3((KC * DD + 255) / 256), dim3(256), 0, stream,
                     out_centers, cnt, loss_acc, keys);
  hipLaunchKernelGGL(k_rownorm, dim3(NS * 8 / 256), dim3(256), 0, stream,
                     E, x2, NS);
  hipLaunchKernelGGL(k_rownorm, dim3(KC * 8 / 256), dim3(256), 0, stream,
                     C, c2, KC);
  hipLaunchKernelGGL(k_argmin, dim3(NS / BM, KC / BN), dim3(256), 0, stream,
                     E, C, x2, c2, keys);
  hipLaunchKernelGGL(k_accum, dim3(1024), dim3(256), 0, stream,
                     E, C, keys, out_centers, cnt, loss_acc, out_labels);
  hipLaunchKernelGGL(k_final, dim3((KC * DD + 255) / 256), dim3(256), 0, stream,
                     C, counts0, cnt, out_centers, out_counts, out_loss, loss_acc);
}

// Round 4
// 1766.967 us; speedup vs baseline: 1.4916x; 1.1648x over previous
//
#include <hip/hip_runtime.h>

typedef short bf16x8 __attribute__((ext_vector_type(8)));
typedef float f32x4 __attribute__((ext_vector_type(4)));

#define NS 131072
#define KC 2048
#define DD 256
#define SMARGIN 0.02f

struct Rec16 { float m1, m2, m3; unsigned ii; };  // ii = i1 | (i2<<16)

// ---------------- helpers ----------------
__device__ __forceinline__ unsigned short f2bf(float x) {
  unsigned u = __float_as_uint(x);
  unsigned r = (u + 0x7fffu + ((u >> 16) & 1u)) >> 16;
  return (unsigned short)r;
}
__device__ __forceinline__ float bf2f(unsigned short b) {
  return __uint_as_float(((unsigned)b) << 16);
}

__device__ __forceinline__ void async16(void* lds, const void* g) {
  __builtin_amdgcn_global_load_lds(
      (const __attribute__((address_space(1))) unsigned*)g,
      (__attribute__((address_space(3))) unsigned*)lds, 16, 0, 0);
}

__device__ __forceinline__ void rec_ins(float& m1, float& m2, float& m3,
                                        int& i1, int& i2, float q, int i) {
  if (q < m1 || (q == m1 && i < i1)) {
    m3 = m2; m2 = m1; i2 = i1; m1 = q; i1 = i;
  } else if (q < m2 || (q == m2 && i < i2)) {
    m3 = m2; m2 = q; i2 = i;
  } else if (q < m3) {
    m3 = q;
  }
}

// exact fp32 distance: bit-identical to the verified round-2/3 chain
__device__ __forceinline__ float dist_exact(const float* __restrict__ E,
                                            const float* __restrict__ C,
                                            const float* __restrict__ x2,
                                            const float* __restrict__ c2,
                                            int row, int j) {
  const float* e = E + (size_t)row * DD;
  const float* c = C + (size_t)j * DD;
  float acc = 0.0f;
  #pragma unroll 8
  for (int k = 0; k < DD; ++k) acc = fmaf(e[k], c[k], acc);
  return __fadd_rn(__fsub_rn(x2[row], __fmul_rn(2.0f, acc)), c2[j]);
}

// ---------------- init ----------------
__global__ void k_init(float* __restrict__ segc, int* __restrict__ cnt,
                       double* __restrict__ loss, int* __restrict__ npairs,
                       int* __restrict__ nscan) {
  int i = blockIdx.x * 256 + threadIdx.x;
  if (i < KC * DD) segc[i] = 0.0f;
  if (i < KC) cnt[i] = 0;
  if (i == 0) { *loss = 0.0; *npairs = 0; *nscan = 0; }
}

// ---------------- row norms, numpy-pairwise-exact fp32 (proven) ----------
__global__ __launch_bounds__(256) void k_rownorm(const float* __restrict__ A,
                                                 float* __restrict__ out,
                                                 int nrows) {
  int g = blockIdx.x * 256 + threadIdx.x;
  int row = g >> 3;
  int l = g & 7;
  if (row >= nrows) return;
  const float* p = A + (size_t)row * DD;
  float halfs[2];
  #pragma unroll
  for (int h = 0; h < 2; ++h) {
    const float* q = p + h * 128;
    float x = q[l];
    float r = __fmul_rn(x, x);
    #pragma unroll
    for (int i = 8; i < 128; i += 8) {
      float y = q[i + l];
      r = __fadd_rn(r, __fmul_rn(y, y));
    }
    float t = __fadd_rn(r, __shfl_xor(r, 1));
    t = __fadd_rn(t, __shfl_xor(t, 2));
    t = __fadd_rn(t, __shfl_xor(t, 4));
    halfs[h] = t;
  }
  if (l == 0) out[row] = __fadd_rn(halfs[0], halfs[1]);
}

// ---------------- f32 -> (hi, lo) bf16 split ----------------
__global__ __launch_bounds__(256) void k_split(const float* __restrict__ src,
                                               unsigned short* __restrict__ hi,
                                               unsigned short* __restrict__ lo,
                                               int n8) {
  int g = blockIdx.x * 256 + threadIdx.x;
  if (g >= n8) return;
  const float4* s = (const float4*)src;
  float4 v0 = s[(size_t)g * 2], v1 = s[(size_t)g * 2 + 1];
  float xs[8] = {v0.x, v0.y, v0.z, v0.w, v1.x, v1.y, v1.z, v1.w};
  ushort hv[8], lv[8];
  #pragma unroll
  for (int i = 0; i < 8; ++i) {
    unsigned short h = f2bf(xs[i]);
    hv[i] = h;
    lv[i] = f2bf(xs[i] - bf2f(h));
  }
  *(ulonglong2*)(hi + (size_t)g * 8) = *(ulonglong2*)hv;
  *(ulonglong2*)(lo + (size_t)g * 8) = *(ulonglong2*)lv;
}

// ---------------- MFMA screening GEMM + per-row approx top-3 ------------
// 128x128 tile, BK=64, 4 waves (2x2), K' = 768 (hi*hi | hi*lo | lo*hi)
__global__ __launch_bounds__(256) void k_screen(
    const unsigned short* __restrict__ Ehi, const unsigned short* __restrict__ Elo,
    const unsigned short* __restrict__ Chi, const unsigned short* __restrict__ Clo,
    const float* __restrict__ c2, Rec16* __restrict__ recs, int chunkRow0) {
  __shared__ char smem[32768];  // A[128][64] bf16 (16K) | B[128][64] bf16 (16K)

  const int tid = threadIdx.x;
  const int wave = tid >> 6, lane = tid & 63;
  const int ln15 = lane & 15, ln4 = lane >> 4;
  const int wr = wave >> 1, wc = wave & 1;
  const int rowA0 = blockIdx.y * 128;   // chunk-local row base
  const int colB0 = blockIdx.x * 128;   // global col base

  f32x4 acc[4][4];
  #pragma unroll
  for (int m = 0; m < 4; ++m)
    #pragma unroll
    for (int n = 0; n < 4; ++n) acc[m][n] = (f32x4){0.f, 0.f, 0.f, 0.f};

  // source element-offset swizzle: chunk' = chunk ^ (row&7), row&7 == lane>>3
  const int rsw = ((lane & 7) ^ (lane >> 3)) << 3;

  for (int kc = 0; kc < 12; ++kc) {
    const int part = kc >> 2;  // 0: hi*hi, 1: hi*lo, 2: lo*hi
    const unsigned short* asrc = (part == 2) ? Elo : Ehi;
    const unsigned short* bsrc = (part == 1) ? Clo : Chi;
    const int k0 = (kc & 3) * 64;

    __syncthreads();  // prior compute done before overwrite
    #pragma unroll
    for (int t = 0; t < 4; ++t) {
      int round = wave * 4 + t;
      int r = round * 8 + (lane >> 3);
      async16(smem + round * 1024,
              asrc + ((size_t)(rowA0 + r) << 8) + k0 + rsw);
    }
    #pragma unroll
    for (int t = 0; t < 4; ++t) {
      int round = wave * 4 + t;
      int c = round * 8 + (lane >> 3);
      async16(smem + 16384 + round * 1024,
              bsrc + ((size_t)(colB0 + c) << 8) + k0 + rsw);
    }
    __syncthreads();  // vmcnt(0) drain: tiles ready

    #pragma unroll
    for (int ks = 0; ks < 2; ++ks) {
      bf16x8 a[4], b[4];
      const int swz = ((ks * 4 + ln4) ^ (ln15 & 7)) << 4;
      #pragma unroll
      for (int m = 0; m < 4; ++m)
        a[m] = *(const bf16x8*)(smem + (wr * 64 + m * 16 + ln15) * 128 + swz);
      #pragma unroll
      for (int n = 0; n < 4; ++n)
        b[n] = *(const bf16x8*)(smem + 16384 + (wc * 64 + n * 16 + ln15) * 128 + swz);
      #pragma unroll
      for (int m = 0; m < 4; ++m)
        #pragma unroll
        for (int n = 0; n < 4; ++n)
          acc[m][n] = __builtin_amdgcn_mfma_f32_16x16x32_bf16(a[m], b[n], acc[m][n], 0, 0, 0);
    }
  }

  // epilogue: q = c2 - 2*dot ; per-row top-3 over this block's 128 cols
  __syncthreads();
  float* mb = (float*)smem;  // [128 rows][2 wc][4 words]
  #pragma unroll
  for (int m = 0; m < 4; ++m) {
    #pragma unroll
    for (int rr = 0; rr < 4; ++rr) {
      float m1 = 3.4e38f, m2 = 3.4e38f, m3 = 3.4e38f;
      int i1 = 0xffff, i2 = 0xffff;
      #pragma unroll
      for (int n = 0; n < 4; ++n) {
        int col = colB0 + wc * 64 + n * 16 + ln15;
        float q = fmaf(-2.0f, acc[m][n][rr], c2[col]);
        rec_ins(m1, m2, m3, i1, i2, q, col);
      }
      #pragma unroll
      for (int msk = 1; msk <= 8; msk <<= 1) {
        float o1 = __shfl_xor(m1, msk), o2 = __shfl_xor(m2, msk), o3 = __shfl_xor(m3, msk);
        int oi1 = __shfl_xor(i1, msk), oi2 = __shfl_xor(i2, msk);
        rec_ins(m1, m2, m3, i1, i2, o1, oi1);
        rec_ins(m1, m2, m3, i1, i2, o2, oi2);
        m3 = fminf(m3, o3);
      }
      if (ln15 == 0) {
        int row = wr * 64 + m * 16 + ln4 * 4 + rr;
        float* p = mb + (row * 2 + wc) * 4;
        p[0] = m1; p[1] = m2; p[2] = m3;
        ((unsigned*)p)[3] = (unsigned)i1 | ((unsigned)i2 << 16);
      }
    }
  }
  __syncthreads();
  if (tid < 128) {
    const float* p0 = mb + (tid * 2) * 4;
    const float* p1 = mb + (tid * 2 + 1) * 4;
    float m1 = p0[0], m2 = p0[1], m3 = p0[2];
    unsigned ii = ((const unsigned*)p0)[3];
    int i1 = (int)(ii & 0xffffu), i2 = (int)(ii >> 16);
    unsigned jj = ((const unsigned*)p1)[3];
    rec_ins(m1, m2, m3, i1, i2, p1[0], (int)(jj & 0xffffu));
    rec_ins(m1, m2, m3, i1, i2, p1[1], (int)(jj >> 16));
    m3 = fminf(m3, p1[2]);
    Rec16 out;
    out.m1 = m1; out.m2 = m2; out.m3 = m3;
    out.ii = (unsigned)i1 | ((unsigned)i2 << 16);
    recs[((size_t)(chunkRow0 + rowA0 + tid) << 4) + blockIdx.x] = out;
  }
}

// ---------------- merge 16 col-block records; classify rows -------------
__global__ __launch_bounds__(256) void k_merge(
    const Rec16* __restrict__ recs, int* __restrict__ labels,
    int4* __restrict__ pairs, int* __restrict__ scans,
    int* __restrict__ npairs, int* __restrict__ nscan) {
  int row = blockIdx.x * 256 + threadIdx.x;
  const Rec16* r = recs + ((size_t)row << 4);
  Rec16 a = r[0];
  float m1 = a.m1, m2 = a.m2, m3 = a.m3;
  int i1 = (int)(a.ii & 0xffffu), i2 = (int)(a.ii >> 16);
  #pragma unroll
  for (int cb = 1; cb < 16; ++cb) {
    Rec16 b = r[cb];
    rec_ins(m1, m2, m3, i1, i2, b.m1, (int)(b.ii & 0xffffu));
    rec_ins(m1, m2, m3, i1, i2, b.m2, (int)(b.ii >> 16));
    m3 = fminf(m3, b.m3);
  }
  labels[row] = i1;  // provisional / final for the direct case
  if (m2 <= m1 + SMARGIN) {
    if (m3 <= m1 + SMARGIN) {
      int s = atomicAdd(nscan, 1); scans[s] = row;
    } else {
      int p = atomicAdd(npairs, 1); pairs[p] = make_int4(row, i1, i2, 0);
    }
  }
}

// ---------------- exact rescore: 2-candidate rows ----------------
__global__ __launch_bounds__(256) void k_pairs(
    const float* __restrict__ E, const float* __restrict__ C,
    const float* __restrict__ x2, const float* __restrict__ c2,
    const int4* __restrict__ pairs, const int* __restrict__ npairs,
    int* __restrict__ labels) {
  int n = *npairs;
  int stride = gridDim.x * 256;
  for (int i = blockIdx.x * 256 + threadIdx.x; i < n; i += stride) {
    int4 p = pairs[i];
    float d1 = dist_exact(E, C, x2, c2, p.x, p.y);
    float d2 = dist_exact(E, C, x2, c2, p.x, p.z);
    labels[p.x] = (d2 < d1 || (d2 == d1 && p.z < p.y)) ? p.z : p.y;
  }
}

// ---------------- exact rescore: full-scan rows ----------------
__global__ __launch_bounds__(256) void k_scan(
    const float* __restrict__ E, const float* __restrict__ C,
    const float* __restrict__ x2, const float* __restrict__ c2,
    const int* __restrict__ scans, const int* __restrict__ nscan,
    int* __restrict__ labels) {
  __shared__ float sd[256];
  __shared__ int sj[256];
  int ns = *nscan;
  for (int s = blockIdx.x; s < ns; s += gridDim.x) {
    int row = scans[s];
    float bd = 3.4e38f; int bj = 0x7fffffff;
    for (int jj = 0; jj < 8; ++jj) {
      int j = jj * 256 + threadIdx.x;
      float d = dist_exact(E, C, x2, c2, row, j);
      if (d < bd || (d == bd && j < bj)) { bd = d; bj = j; }
    }
    sd[threadIdx.x] = bd; sj[threadIdx.x] = bj;
    __syncthreads();
    for (int st = 128; st > 0; st >>= 1) {
      if (threadIdx.x < st) {
        float od = sd[threadIdx.x + st]; int oj = sj[threadIdx.x + st];
        if (od < sd[threadIdx.x] || (od == sd[threadIdx.x] && oj < sj[threadIdx.x])) {
          sd[threadIdx.x] = od; sj[threadIdx.x] = oj;
        }
      }
      __syncthreads();
    }
    if (threadIdx.x == 0) labels[row] = sj[0];
    __syncthreads();
  }
}

// ---------------- accumulate seg sums, counts, loss; emit float labels ---
__global__ __launch_bounds__(256) void k_accum(
    const float* __restrict__ E, const float* __restrict__ C,
    const int* __restrict__ labels, float* __restrict__ seg,
    int* __restrict__ cnt, double* __restrict__ loss,
    float* __restrict__ out_labels) {
  int d = threadIdx.x;
  double lpd = 0.0;
  for (int row = blockIdx.x; row < NS; row += gridDim.x) {
    int lab = labels[row];
    float x = E[(size_t)row * DD + d];
    float c = C[(size_t)lab * DD + d];
    unsafeAtomicAdd(&seg[(size_t)lab * DD + d], x);
    float diff = x - c;
    lpd += (double)diff * (double)diff;
    if (d == 0) {
      atomicAdd(&cnt[lab], 1);
      out_labels[row] = (float)lab;
    }
  }
  #pragma unroll
  for (int o = 32; o >= 1; o >>= 1) lpd += __shfl_down(lpd, o);
  __shared__ double wsum[4];
  int lane = threadIdx.x & 63, wave = threadIdx.x >> 6;
  if (lane == 0) wsum[wave] = lpd;
  __syncthreads();
  if (threadIdx.x == 0) {
    double t = wsum[0] + wsum[1] + wsum[2] + wsum[3];
    unsafeAtomicAdd(loss, t);
  }
}

// ---------------- finalize centers, counts, loss ----------------
__global__ void k_final(const float* __restrict__ C, const int* __restrict__ counts0,
                        const int* __restrict__ cnt, float* __restrict__ out_centers,
                        float* __restrict__ out_counts, float* __restrict__ out_loss,
                        const double* __restrict__ loss) {
  int i = blockIdx.x * 256 + threadIdx.x;
  if (i < KC * DD) {
    int k = i >> 8;
    float c0 = (float)counts0[k];
    float nc = (float)(counts0[k] + cnt[k]);
    out_centers[i] = (c0 * C[i] + out_centers[i]) / nc;
  }
  if (i < KC) out_counts[i] = (float)(counts0[i] + cnt[i]);
  if (i == 0) out_loss[0] = (float)(loss[0] / (double)NS);
}

extern "C" void kernel_launch(void* const* d_in, const int* in_sizes, int n_in,
                              void* d_out, int out_size, void* d_ws, size_t ws_size,
                              hipStream_t stream) {
  const float* E = (const float*)d_in[0];
  const float* C = (const float*)d_in[1];
  const int* counts0 = (const int*)d_in[2];

  float* out = (float*)d_out;
  float* out_labels  = out;                     // [NS]
  float* out_loss    = out + NS;                // [1]
  float* out_centers = out + NS + 1;            // [KC*DD] (doubles as seg acc)
  float* out_counts  = out + NS + 1 + KC * DD;  // [KC]

  char* ws = (char*)d_ws;
  size_t o = 0;
  auto alloc = [&](size_t bytes) -> void* {
    void* p = ws + o;
    o += (bytes + 255) & ~(size_t)255;
    return p;
  };
  double* loss_acc = (double*)alloc(256);  // loss @0, npairs @16, nscan @20
  int* npairs = (int*)((char*)loss_acc + 16);
  int* nscan  = (int*)((char*)loss_acc + 20);
  int*   labels = (int*)alloc(4 * (size_t)NS);
  float* x2     = (float*)alloc(4 * (size_t)NS);
  float* c2     = (float*)alloc(4 * KC);
  int*   cnt    = (int*)alloc(4 * KC);
  unsigned short* Chi = (unsigned short*)alloc(2 * (size_t)KC * DD);
  unsigned short* Clo = (unsigned short*)alloc(2 * (size_t)KC * DD);
  Rec16* recs   = (Rec16*)alloc(sizeof(Rec16) * (size_t)NS * 16);
  int4*  pairs  = (int4*)alloc(16 * (size_t)NS);
  int*   scans  = (int*)alloc(4 * (size_t)NS);

  // chunk size for E hi/lo arrays, adaptive to ws_size
  int CH = 16384;
  while (CH > 2048 && o + 2 * (2 * (size_t)CH * DD) > ws_size) CH >>= 1;
  unsigned short* Ehi = (unsigned short*)alloc(2 * (size_t)CH * DD);
  unsigned short* Elo = (unsigned short*)alloc(2 * (size_t)CH * DD);
  int NCH = NS / CH;

  hipLaunchKernelGGL(k_init, dim3((KC * DD + 255) / 256), dim3(256), 0, stream,
                     out_centers, cnt, loss_acc, npairs, nscan);
  hipLaunchKernelGGL(k_rownorm, dim3(NS * 8 / 256), dim3(256), 0, stream, E, x2, NS);
  hipLaunchKernelGGL(k_rownorm, dim3(KC * 8 / 256), dim3(256), 0, stream, C, c2, KC);
  hipLaunchKernelGGL(k_split, dim3(KC * 32 / 256), dim3(256), 0, stream,
                     C, Chi, Clo, KC * 32);

  for (int ch = 0; ch < NCH; ++ch) {
    hipLaunchKernelGGL(k_split, dim3(CH * 32 / 256), dim3(256), 0, stream,
                       E + (size_t)ch * CH * DD, Ehi, Elo, CH * 32);
    hipLaunchKernelGGL(k_screen, dim3(16, CH / 128), dim3(256), 0, stream,
                       Ehi, Elo, Chi, Clo, c2, recs, ch * CH);
  }

  hipLaunchKernelGGL(k_merge, dim3(NS / 256), dim3(256), 0, stream,
                     recs, labels, pairs, scans, npairs, nscan);
  hipLaunchKernelGGL(k_pairs, dim3(64), dim3(256), 0, stream,
                     E, C, x2, c2, pairs, npairs, labels);
  hipLaunchKernelGGL(k_scan, dim3(128), dim3(256), 0, stream,
                     E, C, x2, c2, scans, nscan, labels);
  hipLaunchKernelGGL(k_accum, dim3(1024), dim3(256), 0, stream,
                     E, C, labels, out_centers, cnt, loss_acc, out_labels);
  hipLaunchKernelGGL(k_final, dim3((KC * DD + 255) / 256), dim3(256), 0, stream,
                     C, counts0, cnt, out_centers, out_counts, out_loss, loss_acc);
}